// Round 2
// baseline (124.769 us; speedup 1.0000x reference)
//
#include <hip/hip_runtime.h>
#include <hip/hip_bf16.h>

// Chamfer distance, p/q: (2, 64, 1024, 4) fp32; components 1..3.
// Single fused kernel. Grid = 128 batches x 2 sides x 4 row-quarters = 1024
// blocks of 256 threads; each thread owns ONE row, loops all 1024 opposite
// points. min_m (qsq[m] - 2*dot) computed as 3 fma + 1 min per pair:
//   - opposite point coords come from wave-uniform global loads -> SMEM
//     (s_load_dwordx4), zero VMEM/LDS cost in the inner loop
//   - opposite norms qsq precomputed once into LDS, read as broadcast
//     ds_read_b128 (4 norms per read, conflict-free)
// Epilogue: d = sqrt(max(min+psq,0)+eps), block reduce, 1 atomicAdd.
// d_out zeroed by a 4-byte memset (atomic accumulation target).

#define TPB 256

__global__ __launch_bounds__(TPB, 4) void chamfer_fused(
    const float4* __restrict__ P, const float4* __restrict__ Q,
    float* __restrict__ out)
{
    __shared__ float sq[1024];
    __shared__ float wsum[TPB / 64];

    const int blk     = blockIdx.x;
    const int batch   = blk >> 3;         // 0..127 (c*64+b)
    const int side    = (blk >> 2) & 1;   // 0: min over q for p-rows; 1: swap
    const int quarter = blk & 3;          // which 256 rows this block owns
    const int t       = threadIdx.x;
    const int base    = batch << 10;

    const float4* __restrict__ ownb = (side ? Q : P) + base;
    const float4* __restrict__ oppb = (side ? P : Q) + base;

    // Prologue: norms of all 1024 opposite points -> LDS (coalesced loads).
#pragma unroll
    for (int i = 0; i < 4; ++i) {
        float4 v = oppb[(i << 8) + t];
        sq[(i << 8) + t] = v.y * v.y + v.z * v.z + v.w * v.w;
    }

    // Own row (per-lane), with -2 folded in.
    float4 r = ownb[(quarter << 8) + t];
    const float rx2 = -2.0f * r.y, ry2 = -2.0f * r.z, rz2 = -2.0f * r.w;
    const float psq = r.y * r.y + r.z * r.z + r.w * r.w;
    float acc = 3.4e38f;
    __syncthreads();

    for (int m0 = 0; m0 < 1024; m0 += 4) {
        // broadcast read: 4 norms in one ds_read_b128
        float4 q4 = *reinterpret_cast<const float4*>(&sq[m0]);
        float qs[4] = {q4.x, q4.y, q4.z, q4.w};
#pragma unroll
        for (int mi = 0; mi < 4; ++mi) {
            float4 qv = oppb[m0 + mi];   // wave-uniform -> s_load_dwordx4
            float v = fmaf(rx2, qv.y,
                      fmaf(ry2, qv.z,
                      fmaf(rz2, qv.w, qs[mi])));
            acc = fminf(acc, v);
        }
    }

    float d = sqrtf(fmaxf(acc + psq, 0.0f) + 1e-12f);

    // Block reduction: wave shuffle, then cross-wave via LDS, one atomic.
#pragma unroll
    for (int off = 32; off; off >>= 1) d += __shfl_down(d, off, 64);
    if ((t & 63) == 0) wsum[t >> 6] = d;
    __syncthreads();
    if (t == 0) {
        atomicAdd(out, wsum[0] + wsum[1] + wsum[2] + wsum[3]);
    }
}

extern "C" void kernel_launch(void* const* d_in, const int* in_sizes, int n_in,
                              void* d_out, int out_size, void* d_ws, size_t ws_size,
                              hipStream_t stream) {
    const float4* P = (const float4*)d_in[0];
    const float4* Q = (const float4*)d_in[1];
    float* out = (float*)d_out;

    hipMemsetAsync(d_out, 0, sizeof(float), stream);
    chamfer_fused<<<dim3(128 * 2 * 4), dim3(TPB), 0, stream>>>(P, Q, out);
}

// Round 3
// 90.302 us; speedup vs baseline: 1.3817x; 1.3817x over previous
//
#include <hip/hip_runtime.h>
#include <hip/hip_bf16.h>

// Chamfer distance, p/q: (2, 64, 1024, 4) fp32; components 1..3.
// Kernel 1: grid = 128 batches x 2 sides x 4 m-chunks = 1024 blocks x 128 thr.
//   Each block: all 1024 rows (R=8/thread, stride-128) x 256 opposite points
//   staged in LDS as (-2x, -2y, -2z, qsq)  -> pair = 3 v_fma + 1 v_min.
//   One broadcast ds_read_b128 feeds 64 lanes x 8 rows = 512 pairs
//   (32 VALU-instr : 1 LDS-instr > 24:1 CU balance -> VALU-bound).
//   Partial min (+ own norm) per (row, chunk) -> 4 MB workspace.
// Kernel 2: min over 4 chunks, clamp+eps+sqrt, block-reduce, atomicAdd.

#define TPB1 128
#define RPT 8          // rows per thread
#define SPLITS 4       // m-chunks per (batch,side)
#define CHUNK 256      // 1024 / SPLITS
#define RTPB 256
#define RBLOCKS 256

__global__ __launch_bounds__(TPB1) void chamfer_min(
    const float4* __restrict__ P, const float4* __restrict__ Q,
    float* __restrict__ part)
{
    __shared__ float4 tile[CHUNK];
    const int blk   = blockIdx.x;
    const int batch = blk >> 3;        // 0..127
    const int side  = (blk >> 2) & 1;  // 0: rows from P, opp Q; 1: swapped
    const int j     = blk & 3;         // m-chunk
    const int t     = threadIdx.x;
    const int base  = batch << 10;

    const float4* __restrict__ ownb = (side ? Q : P) + base;
    const float4* __restrict__ oppb = (side ? P : Q) + base;

    // Stage this block's 256-point opposite chunk with -2 and norm folded in.
#pragma unroll
    for (int i = 0; i < CHUNK / TPB1; ++i) {
        float4 v = oppb[(j << 8) + i * TPB1 + t];
        float qs = v.y * v.y + v.z * v.z + v.w * v.w;
        tile[i * TPB1 + t] = make_float4(-2.0f * v.y, -2.0f * v.z, -2.0f * v.w, qs);
    }

    float rx[RPT], ry[RPT], rz[RPT], acc[RPT];
#pragma unroll
    for (int r = 0; r < RPT; ++r) {
        float4 v = ownb[t + (r << 7)];     // rows t, t+128, ... (coalesced)
        rx[r] = v.y; ry[r] = v.z; rz[r] = v.w;
        acc[r] = 3.4e38f;
    }
    __syncthreads();

#pragma unroll 2
    for (int m = 0; m < CHUNK; ++m) {
        float4 qv = tile[m];               // broadcast ds_read_b128
#pragma unroll
        for (int r = 0; r < RPT; ++r) {
            float v = fmaf(qv.x, rx[r],
                      fmaf(qv.y, ry[r],
                      fmaf(qv.z, rz[r], qv.w)));
            acc[r] = fminf(acc[r], v);
        }
    }

    // part[blk*1024 + row] = min_chunk d2-ish (+ own norm)
    float* outp = part + (blk << 10);
#pragma unroll
    for (int r = 0; r < RPT; ++r) {
        float psq = rx[r] * rx[r] + ry[r] * ry[r] + rz[r] * rz[r];
        outp[t + (r << 7)] = acc[r] + psq;
    }
}

__global__ __launch_bounds__(RTPB) void chamfer_reduce(
    const float* __restrict__ part, float* __restrict__ out)
{
    __shared__ float ws[RTPB / 64];
    const int t = threadIdx.x;
    float sum = 0.0f;
    // 2 sides * 128 batches * 1024 rows = 2^18 row-slots
    for (int rid = blockIdx.x * RTPB + t; rid < (1 << 18); rid += RTPB * RBLOCKS) {
        const int bs  = rid >> 10;         // (batch*2+side)
        const int row = rid & 1023;
        const float* pp = part + (bs << 12) + row;
        float v = fminf(fminf(pp[0], pp[1 << 10]),
                        fminf(pp[2 << 10], pp[3 << 10]));
        sum += sqrtf(fmaxf(v, 0.0f) + 1e-12f);
    }
#pragma unroll
    for (int off = 32; off; off >>= 1) sum += __shfl_down(sum, off, 64);
    if ((t & 63) == 0) ws[t >> 6] = sum;
    __syncthreads();
    if (t == 0) atomicAdd(out, ws[0] + ws[1] + ws[2] + ws[3]);
}

extern "C" void kernel_launch(void* const* d_in, const int* in_sizes, int n_in,
                              void* d_out, int out_size, void* d_ws, size_t ws_size,
                              hipStream_t stream) {
    const float4* P = (const float4*)d_in[0];
    const float4* Q = (const float4*)d_in[1];
    float* out = (float*)d_out;
    float* part = (float*)d_ws;   // 1024 blocks * 1024 rows * 4 B = 4 MB

    hipMemsetAsync(d_out, 0, sizeof(float), stream);
    chamfer_min<<<dim3(128 * 2 * SPLITS), dim3(TPB1), 0, stream>>>(P, Q, part);
    chamfer_reduce<<<dim3(RBLOCKS), dim3(RTPB), 0, stream>>>(part, out);
}

// Round 4
// 87.956 us; speedup vs baseline: 1.4185x; 1.0267x over previous
//
#include <hip/hip_runtime.h>
#include <hip/hip_bf16.h>

// Chamfer distance, p/q: (2, 64, 1024, 4) fp32; components 1..3.
// Kernel 1: grid = 128 batches x 2 sides x 8 m-chunks = 2048 blocks x 128 thr
//   (8 blocks/CU -> 4 waves/SIMD for latency hiding).
//   Each block: 1024 rows (R=8/thread, stride-128) x 128 opposite points
//   staged in LDS as (-2x, -2y, -2z, qsq) -> pair = 3 v_fma + 1 v_min.
//   Inner loop is software-pipelined 2 deep: ds_read_b128 for m+2 issues
//   before the 32 FMAs on m, covering ~120cyc LDS latency with ~128cyc VALU.
//   Partial min (+ own norm) per (row, chunk) -> 8 MB workspace.
// Kernel 2: min over 8 chunks, clamp+eps+sqrt, block-reduce, atomicAdd.

#define TPB1 128
#define RPT 8          // rows per thread
#define SPLITS 8       // m-chunks per (batch,side)
#define CHUNK 128      // 1024 / SPLITS
#define RTPB 256
#define RBLOCKS 256

__global__ __launch_bounds__(TPB1, 4) void chamfer_min(
    const float4* __restrict__ P, const float4* __restrict__ Q,
    float* __restrict__ part)
{
    __shared__ float4 tile[CHUNK + 2];   // +2: prefetch overrun pad
    const int blk   = blockIdx.x;
    const int batch = blk >> 4;        // 0..127
    const int side  = (blk >> 3) & 1;  // 0: rows from P, opp Q; 1: swapped
    const int j     = blk & 7;         // m-chunk
    const int t     = threadIdx.x;
    const int base  = batch << 10;

    const float4* __restrict__ ownb = (side ? Q : P) + base;
    const float4* __restrict__ oppb = (side ? P : Q) + base;

    // Stage this block's 128-point opposite chunk, -2 and norm folded in.
    {
        float4 v = oppb[(j << 7) + t];
        float qs = v.y * v.y + v.z * v.z + v.w * v.w;
        tile[t] = make_float4(-2.0f * v.y, -2.0f * v.z, -2.0f * v.w, qs);
    }

    float rx[RPT], ry[RPT], rz[RPT], acc[RPT];
#pragma unroll
    for (int r = 0; r < RPT; ++r) {
        float4 v = ownb[t + (r << 7)];     // rows t, t+128, ... (coalesced)
        rx[r] = v.y; ry[r] = v.z; rz[r] = v.w;
        acc[r] = 3.4e38f;
    }
    __syncthreads();

    float4 a = tile[0];
    float4 b = tile[1];
    for (int m = 0; m < CHUNK; m += 2) {
        float4 n0 = tile[m + 2];           // prefetch (pad makes this safe)
#pragma unroll
        for (int r = 0; r < RPT; ++r) {
            float v = fmaf(a.x, rx[r], fmaf(a.y, ry[r], fmaf(a.z, rz[r], a.w)));
            acc[r] = fminf(acc[r], v);
        }
        float4 n1 = tile[m + 3];
#pragma unroll
        for (int r = 0; r < RPT; ++r) {
            float v = fmaf(b.x, rx[r], fmaf(b.y, ry[r], fmaf(b.z, rz[r], b.w)));
            acc[r] = fminf(acc[r], v);
        }
        a = n0; b = n1;
    }

    // part[blk*1024 + row] = min over this chunk (+ own norm)
    float* outp = part + (blk << 10);
#pragma unroll
    for (int r = 0; r < RPT; ++r) {
        float psq = rx[r] * rx[r] + ry[r] * ry[r] + rz[r] * rz[r];
        outp[t + (r << 7)] = acc[r] + psq;
    }
}

__global__ __launch_bounds__(RTPB) void chamfer_reduce(
    const float* __restrict__ part, float* __restrict__ out)
{
    __shared__ float ws[RTPB / 64];
    const int t = threadIdx.x;
    float sum = 0.0f;
    // 2 sides * 128 batches * 1024 rows = 2^18 row-slots
    for (int rid = blockIdx.x * RTPB + t; rid < (1 << 18); rid += RTPB * RBLOCKS) {
        const int bs  = rid >> 10;         // (batch*2+side), 0..255
        const int row = rid & 1023;
        const float* pp = part + (bs << 13) + row;
        float v = 3.4e38f;
#pragma unroll
        for (int k = 0; k < SPLITS; ++k) v = fminf(v, pp[k << 10]);
        sum += sqrtf(fmaxf(v, 0.0f) + 1e-12f);
    }
#pragma unroll
    for (int off = 32; off; off >>= 1) sum += __shfl_down(sum, off, 64);
    if ((t & 63) == 0) ws[t >> 6] = sum;
    __syncthreads();
    if (t == 0) atomicAdd(out, ws[0] + ws[1] + ws[2] + ws[3]);
}

extern "C" void kernel_launch(void* const* d_in, const int* in_sizes, int n_in,
                              void* d_out, int out_size, void* d_ws, size_t ws_size,
                              hipStream_t stream) {
    const float4* P = (const float4*)d_in[0];
    const float4* Q = (const float4*)d_in[1];
    float* out = (float*)d_out;
    float* part = (float*)d_ws;   // 2048 blocks * 1024 rows * 4 B = 8 MB

    hipMemsetAsync(d_out, 0, sizeof(float), stream);
    chamfer_min<<<dim3(128 * 2 * SPLITS), dim3(TPB1), 0, stream>>>(P, Q, part);
    chamfer_reduce<<<dim3(RBLOCKS), dim3(RTPB), 0, stream>>>(part, out);
}